// Round 12
// baseline (101.052 us; speedup 1.0000x reference)
//
#include <hip/hip_runtime.h>
#include <hip/hip_bf16.h>
#include <stdint.h>

// Problem dims
#define M_DIM 8000
#define K_DIM 120
#define N_DIM 8000
// 8000 = 125 * 64 exactly -> bm tiles 0..124 fully valid, bm=125 all-pad.
#define TILES_M 126
#define TILES_N 63

typedef __attribute__((ext_vector_type(8))) __bf16 bf16x8;
typedef __attribute__((ext_vector_type(4))) float f32x4;
typedef __attribute__((ext_vector_type(8))) unsigned short u16x8;

__device__ __forceinline__ unsigned short f2bf(float f) {
  unsigned int u = __builtin_bit_cast(unsigned int, f);
  u += 0x7FFFu + ((u >> 16) & 1u);   // round-to-nearest-even
  return (unsigned short)(u >> 16);
}

// Single fused kernel: per-block operand conversion -> MFMA -> LDS-transpose
// epilogue -> NT stores. 64x128 tile, 4 waves, single K-tile (K_pad=128).
// LDS: As [0,16K) row-swizzle (row&7)<<4; Bs [16K,48K) row-swizzle (row&15)<<4;
// tbuf [64][132] f32 overlays [0,33.8K). 48KB -> 3 blocks/CU.
__global__ __launch_bounds__(256, 3) void fused_gemm_kernel(const float* __restrict__ A,
                                                            const float* __restrict__ B,
                                                            const float* __restrict__ bias,
                                                            float* __restrict__ out) {
  __shared__ __align__(16) char smem[49152];
  char* smemA = smem;            // [64][256B]  bf16 [64][128]
  char* smemB = smem + 16384;    // [128][256B] bf16 [128][128] (B^T slice)
  const int bn = blockIdx.x;     // 0..62  (128-col tiles)
  const int bm = blockIdx.y;     // 0..125 (64-row tiles)
  const int tid  = threadIdx.x;
  const int lane = tid & 63;
  const int wave = tid >> 6;     // 0..3 == 32-col slot
  const int l15 = lane & 15;
  const int kq  = lane >> 4;     // 0..3

  // ---- Stage A: contiguous 30KB f32 slab -> bf16, swizzled ----
  // unit u in [0,1920): row = u/30, g4 = u%30 (float4 index along k).
  // Flat source address = Atile + u*16 (rows are consecutive in A).
  const bool aval = (bm < 125);
  const char* aSrc = (const char*)(A + (size_t)bm * 64 * K_DIM);
#pragma unroll
  for (int p = 0; p < 8; ++p) {
    int u = p * 256 + tid;
    if (u < 1920) {
      float4 f = {0.f, 0.f, 0.f, 0.f};
      if (aval) f = *(const float4*)(aSrc + (size_t)u * 16);
      int row = u / 30;
      int g4  = u - row * 30;
      ushort4 h;
      h.x = f2bf(f.x); h.y = f2bf(f.y); h.z = f2bf(f.z); h.w = f2bf(f.w);
      int off = (g4 * 8) ^ ((row & 7) << 4);
      *(ushort4*)(smemA + row * 256 + off) = h;   // ds_write_b64
    }
  }
  // A pad k in [120,128): 16B zeros per row.
  if (tid < 64) {
    int off = 240 ^ ((tid & 7) << 4);
    *(uint4*)(smemA + tid * 256 + off) = (uint4){0u, 0u, 0u, 0u};
  }

  // ---- Stage B: B[k][n] slice -> B^T bf16, swizzled ----
  // unit u in [0,1920): kg = u>>7 (0..14), nl = u&127. Lane-consecutive nl
  // -> coalesced 256B bursts per k-row.
#pragma unroll
  for (int p = 0; p < 8; ++p) {
    int u = p * 256 + tid;
    if (u < 1920) {
      int kg = u >> 7;
      int nl = u & 127;
      int gn = bn * 128 + nl;
      u16x8 v = (u16x8)0;
      if (gn < N_DIM) {
        const float* src = B + (size_t)(kg * 8) * N_DIM + gn;
#pragma unroll
        for (int j = 0; j < 8; ++j) v[j] = f2bf(src[(size_t)j * N_DIM]);
      }
      int off = (kg * 16) ^ ((nl & 15) << 4);
      *(u16x8*)(smemB + nl * 256 + off) = v;      // ds_write_b128
    }
  }
  // B pad kg=15: 16B zeros per row.
  if (tid < 128) {
    int off = 240 ^ ((tid & 15) << 4);
    *(u16x8*)(smemB + tid * 256 + off) = (u16x8)0;
  }

  __syncthreads();

  // ---- MFMA body (R6-proven geometry) ----
  f32x4 acc[4][2] = {};
#pragma unroll
  for (int ks = 0; ks < 4; ++ks) {
    const int kb = ks * 64 + kq * 16;   // byte offset along K (slot = ks*4+kq)
    bf16x8 a[4], b[2];
#pragma unroll
    for (int m = 0; m < 4; ++m) {
      int row = m * 16 + l15;           // 0..63
      a[m] = *(const bf16x8*)(smemA + (size_t)row * 256 + (kb ^ ((row & 7) << 4)));
    }
#pragma unroll
    for (int n = 0; n < 2; ++n) {
      int row = wave * 32 + n * 16 + l15;   // 0..127
      b[n] = *(const bf16x8*)(smemB + (size_t)row * 256 + (kb ^ ((row & 15) << 4)));
    }
#pragma unroll
    for (int m = 0; m < 4; ++m)
#pragma unroll
      for (int n = 0; n < 2; ++n)
        acc[m][n] = __builtin_amdgcn_mfma_f32_16x16x32_bf16(a[m], b[n], acc[m][n], 0, 0, 0);
  }

  // ---- Epilogue ----
  // C/D layout: col = lane&15, row_in_16 = (lane>>4)*4 + reg   [m89-verified]
  float bv[2];
#pragma unroll
  for (int n = 0; n < 2; ++n) {
    int gcol = bn * 128 + wave * 32 + n * 16 + l15;
    bv[n] = (gcol < N_DIM) ? bias[gcol] : 0.f;
  }

  float* tbuf = (float*)smem;      // [64][132] f32, overlays As/Bs
  __syncthreads();                 // all MFMA reads of As/Bs done
#pragma unroll
  for (int m = 0; m < 4; ++m)
#pragma unroll
    for (int n = 0; n < 2; ++n)
#pragma unroll
      for (int r = 0; r < 4; ++r) {
        int rl = m * 16 + kq * 4 + r;          // 0..63
        int c  = wave * 32 + n * 16 + l15;     // 0..127
        tbuf[rl * 132 + c] = acc[m][n][r] + bv[n];
      }
  __syncthreads();

  // Stream out: each wave instr covers 2 rows x 512B contiguous. NT stores.
  const int c = lane & 31;                     // 16-B chunk within row
  const int gcol0 = bn * 128 + c * 4;
  const bool colok = (gcol0 < N_DIM);          // chunk fully valid (8000%4==0)
#pragma unroll
  for (int j = 0; j < 8; ++j) {
    int row = j * 8 + wave * 2 + (lane >> 5);  // 0..63
    f32x4 v = *(const f32x4*)(tbuf + row * 132 + c * 4);
    if (colok) {
      size_t off = (size_t)(bm * 64 + row) * N_DIM + gcol0;
      __builtin_nontemporal_store(v, (f32x4*)(out + off));
    }
  }
}

extern "C" void kernel_launch(void* const* d_in, const int* in_sizes, int n_in,
                              void* d_out, int out_size, void* d_ws, size_t ws_size,
                              hipStream_t stream) {
  const float* A    = (const float*)d_in[0];
  const float* Bm   = (const float*)d_in[1];
  const float* bias = (const float*)d_in[2];
  float* out = (float*)d_out;
  (void)d_ws; (void)ws_size; (void)in_sizes; (void)n_in; (void)out_size;

  fused_gemm_kernel<<<dim3(TILES_N, TILES_M), dim3(256), 0, stream>>>(A, Bm, bias, out);
}